// Round 6
// baseline (249.317 us; speedup 1.0000x reference)
//
#include <hip/hip_runtime.h>
#include <math.h>

#define B_ 4
#define S_ 2048
#define E_ 1024
#define H_ 16
#define D_ 64
#define M_ (B_*S_)
// 1/sqrt(2048) * log2(e): scale folded into Wq/bq so softmax uses exp2 directly
#define QSCALE (0.022097086912079608f * 1.4426950408889634f)

typedef __bf16 bf16_t;
typedef __bf16 bf16x8 __attribute__((ext_vector_type(8)));
typedef float  f32x4  __attribute__((ext_vector_type(4)));

// async global->LDS, 16B per lane. LDS dest must be linear (base + lane*16).
__device__ __forceinline__ void gload_lds16(const void* g, void* l) {
    __builtin_amdgcn_global_load_lds(
        (const __attribute__((address_space(1))) void*)g,
        (__attribute__((address_space(3))) void*)l, 16, 0, 0);
}
__device__ __forceinline__ bf16x8 ldsx8(const void* p) {
    return __builtin_bit_cast(bf16x8, *(const uint4*)p);
}
__device__ __forceinline__ unsigned short bf16bits(float x) {
    return __builtin_bit_cast(unsigned short, (bf16_t)x);
}
// swizzle for K-tile QK^T A-frag read rows {32c + 8a + 4kf + b}: f = (b + 2a) & 7
__device__ __forceinline__ int fk(int row) { return ((row & 3) + 2 * ((row >> 3) & 3)) & 7; }

// ---------------------------------------------------------------------------
// bf16 MFMA GEMM, C = A[M,K] x Bt[N,K]^T. BK=64, 4 waves, wave tile (BM/2)x(BN/2).
// Grid flattened + bijective XCD swizzle (requires nwg % 8 == 0).
// MODE 0: f32 out + bias. MODE 1: bf16 out + bias + exact GELU.
// MODE 2: QKV scatter; Q bias scaled by QSCALE; V written transposed to ob2
//         as vt[bh][d][s].
// ---------------------------------------------------------------------------
template<int BM, int BN, int MODE>
__global__ __launch_bounds__(256) void gemm_bf16(
    const bf16_t* __restrict__ A, const bf16_t* __restrict__ Bt,
    float* __restrict__ outf,
    bf16_t* __restrict__ ob0, bf16_t* __restrict__ ob1, bf16_t* __restrict__ ob2,
    const float* __restrict__ bias0, const float* __restrict__ bias1,
    const float* __restrict__ bias2,
    int M, int N, int K)
{
    constexpr int FM = BM / 32, FN = BN / 32;
    __shared__ bf16_t As[BM * 64];
    __shared__ bf16_t Bs[BN * 64];

    const int tid = threadIdx.x;
    const int w   = tid >> 6;
    const int wr  = w >> 1, wc = w & 1;
    const int lr  = tid & 15;
    const int lg  = (tid >> 4) & 3;

    // XCD-bijective block swizzle: 8 contiguous chunks, one per XCD
    const int nwg  = gridDim.x * gridDim.y;
    int bidf = blockIdx.y * gridDim.x + blockIdx.x;
    bidf = (bidf & 7) * (nwg >> 3) + (bidf >> 3);
    const int bm = (bidf / gridDim.x) * BM;
    const int bn = (bidf % gridDim.x) * BN;

    f32x4 acc[FM][FN] = {};

    for (int kk = 0; kk < K; kk += 64) {
        __syncthreads();
        #pragma unroll
        for (int i = 0; i < BM / 32; ++i) {
            int idx = i * 256 + tid;
            int row = idx >> 3, slot = idx & 7;
            gload_lds16(A + (size_t)(bm + row) * K + kk + (slot ^ (row & 7)) * 8,
                        (char*)As + idx * 16);
        }
        #pragma unroll
        for (int i = 0; i < BN / 32; ++i) {
            int idx = i * 256 + tid;
            int row = idx >> 3, slot = idx & 7;
            gload_lds16(Bt + (size_t)(bn + row) * K + kk + (slot ^ (row & 7)) * 8,
                        (char*)Bs + idx * 16);
        }
        __syncthreads();

        #pragma unroll
        for (int h = 0; h < 2; ++h) {
            bf16x8 af[FM], bfr[FN];
            #pragma unroll
            for (int m = 0; m < FM; ++m) {
                int row = wr * (BM / 2) + m * 16 + lr;
                af[m] = ldsx8((char*)As + row * 128 + (((4 * h + lg) ^ (row & 7)) << 4));
            }
            #pragma unroll
            for (int n = 0; n < FN; ++n) {
                int col = wc * (BN / 2) + n * 16 + lr;
                bfr[n] = ldsx8((char*)Bs + col * 128 + (((4 * h + lg) ^ (col & 7)) << 4));
            }
            #pragma unroll
            for (int m = 0; m < FM; ++m)
                #pragma unroll
                for (int n = 0; n < FN; ++n)
                    acc[m][n] = __builtin_amdgcn_mfma_f32_16x16x32_bf16(
                        af[m], bfr[n], acc[m][n], 0, 0, 0);
        }
    }

    #pragma unroll
    for (int n = 0; n < FN; ++n) {
        const int gcol = bn + wc * (BN / 2) + n * 16 + lr;
        if constexpr (MODE == 2) {
            const int p = gcol >> 10, nn = gcol & 1023;
            const float bv = (p == 0) ? bias0[nn] * QSCALE
                           : (p == 1) ? bias1[nn] : bias2[nn];
            #pragma unroll
            for (int m = 0; m < FM; ++m) {
                const int grow0 = bm + wr * (BM / 2) + m * 16 + lg * 4;
                if (p == 2) {   // V: write transposed [bh][d][s], 4 s contiguous
                    ushort4 o;
                    o.x = bf16bits(acc[m][n][0] + bv);
                    o.y = bf16bits(acc[m][n][1] + bv);
                    o.z = bf16bits(acc[m][n][2] + bv);
                    o.w = bf16bits(acc[m][n][3] + bv);
                    const int bb = grow0 >> 11, s = grow0 & 2047;
                    *(ushort4*)(ob2 + (((size_t)(bb << 10) + nn) << 11) + s) = o;
                } else {
                    bf16_t* o = (p == 0) ? ob0 : ob1;
                    #pragma unroll
                    for (int r = 0; r < 4; ++r)
                        o[((size_t)(grow0 + r) << 10) + nn] = (bf16_t)(acc[m][n][r] + bv);
                }
            }
        } else {
            const float bv = bias0[gcol];
            #pragma unroll
            for (int m = 0; m < FM; ++m)
                #pragma unroll
                for (int r = 0; r < 4; ++r) {
                    const int grow = bm + wr * (BM / 2) + m * 16 + lg * 4 + r;
                    float v = acc[m][n][r] + bv;
                    if constexpr (MODE == 1) {
                        v = 0.5f * v * (1.0f + erff(v * 0.70710678118654752f));
                        ob0[(size_t)grow * N + gcol] = (bf16_t)v;
                    } else {
                        outf[(size_t)grow * N + gcol] = v;
                    }
                }
        }
    }
}

// ---------------------------------------------------------------------------
// MFMA flash attention, zero-shuffle P path.
// 8 waves x 16 q-rows = QBLK 128, KVBLK=64, double-buffered stage-early.
// grid 1024 = 4 blocks/CU exactly (LDS 40KB, VGPR <= 64 via launch_bounds).
// Swapped QK^T: S^T = mfma(K_frag, Q_frag); A-row->key permutation puts each
// lane's 8 exp'd P values exactly into the K=32 PV B-fragment.
// L accumulated by ones-row MFMA (no per-element adds); exp2-domain scores.
// Mask via fminf{+3e38,-1e9}; exp2(-1e9)=0. 8 bh per XCD for K/V L2 locality.
// ---------------------------------------------------------------------------
__global__ __launch_bounds__(512, 8) void attn_mfma(
    const bf16_t* __restrict__ qg, const bf16_t* __restrict__ kg,
    const bf16_t* __restrict__ vg, const int* __restrict__ mask,
    bf16_t* __restrict__ ctx)
{
    __shared__ bf16_t ks[2][64 * 64];   // [key][d] 128B rows, fk-swizzled
    __shared__ bf16_t vts[2][64 * 64];  // [d][key] 128B rows, row&7-swizzled
    __shared__ float  mrow[S_];

    const int tid = threadIdx.x;
    const int w   = tid >> 6;
    const int lr  = tid & 15;
    const int lg  = (tid >> 4) & 3;

    const int bid = blockIdx.x;
    const int xcd = bid & 7, kidx = bid >> 3;        // kidx in [0,128)
    const int bh  = xcd * 8 + (kidx >> 4);           // 8 bh per XCD
    const int xq  = kidx & 15;                       // 16 q-blocks of 128
    const int b   = bh >> 4, h = bh & 15;
    const int q0w = xq * 128 + w * 16;

    for (int i = tid; i < S_; i += 512)
        mrow[i] = mask[b * S_ + i] ? 3.0e38f : -1.0e9f;

    // Q as B-fragment: lane holds Q[q0w + lr][half*32 + lg*8 + j]
    bf16x8 aq0, aq1;
    {
        const bf16_t* qp = qg + ((size_t)(b * S_ + q0w + lr) << 10) + h * 64 + lg * 8;
        aq0 = ldsx8(qp);
        aq1 = ldsx8(qp + 32);
    }

    // ones A-fragment (row 0 = 1.0) for L-via-MFMA
    bf16x8 onesf;
    {
        bf16_t o1 = (bf16_t)((lr == 0) ? 1.0f : 0.0f);
        #pragma unroll
        for (int j = 0; j < 8; ++j) onesf[j] = o1;
    }

    // precomputed LDS read byte-offsets
    int koff[2][2][2], voff[2][4];
    #pragma unroll
    for (int c = 0; c < 2; ++c) {
        #pragma unroll
        for (int kf1 = 0; kf1 < 2; ++kf1) {
            const int row = c * 32 + 8 * (lr >> 2) + 4 * kf1 + (lr & 3);
            const int f = fk(row);
            koff[c][kf1][0] = row * 128 + ((lg ^ f) << 4);
            koff[c][kf1][1] = row * 128 + (((4 + lg) ^ f) << 4);
        }
        #pragma unroll
        for (int n = 0; n < 4; ++n) {
            const int rowv = n * 16 + lr;
            voff[c][n] = rowv * 128 + (((4 * c + lg) ^ (rowv & 7)) << 4);
        }
    }

    // staging pointers (incremental)
    const int srow = tid >> 3, sslot = tid & 7;
    const bf16_t* kptr = kg + ((size_t)(b * S_ + srow) << 10) + h * 64 + (sslot ^ fk(srow)) * 8;
    const bf16_t* vptr = vg + (((size_t)bh * 64 + srow) << 11) + (sslot ^ (srow & 7)) * 8;
    char* kdst = (char*)ks + tid * 16;
    char* vdst = (char*)vts + tid * 16;

    f32x4 accO[4] = {};
    f32x4 accL = {};

    gload_lds16(kptr, kdst);
    gload_lds16(vptr, vdst);
    kptr += (size_t)64 << 10; vptr += 64;
    __syncthreads();

    int cur = 0;
    for (int t0 = 0; t0 < S_; t0 += 64) {
        if (t0 + 64 < S_) {
            const int nb = (cur ^ 1) << 13;
            gload_lds16(kptr, kdst + nb);
            gload_lds16(vptr, vdst + nb);
            kptr += (size_t)64 << 10; vptr += 64;
        }
        const char* ksb = (const char*)ks + (cur << 13);
        const char* vsb = (const char*)vts + (cur << 13);

        #pragma unroll
        for (int c = 0; c < 2; ++c) {
            unsigned int pw[4];
            #pragma unroll
            for (int kf1 = 0; kf1 < 2; ++kf1) {
                bf16x8 a0 = ldsx8(ksb + koff[c][kf1][0]);
                bf16x8 a1 = ldsx8(ksb + koff[c][kf1][1]);
                f32x4 z = {};
                __builtin_amdgcn_s_setprio(1);
                z = __builtin_amdgcn_mfma_f32_16x16x32_bf16(a0, aq0, z, 0, 0, 0);
                z = __builtin_amdgcn_mfma_f32_16x16x32_bf16(a1, aq1, z, 0, 0, 0);
                __builtin_amdgcn_s_setprio(0);
                const f32x4 cap = *(const f32x4*)&mrow[t0 + c * 32 + 8 * lg + 4 * kf1];
                const float p0 = __builtin_amdgcn_exp2f(fminf(z[0], cap[0]));
                const float p1 = __builtin_amdgcn_exp2f(fminf(z[1], cap[1]));
                const float p2 = __builtin_amdgcn_exp2f(fminf(z[2], cap[2]));
                const float p3 = __builtin_amdgcn_exp2f(fminf(z[3], cap[3]));
                pw[2 * kf1]     = bf16bits(p0) | ((unsigned)bf16bits(p1) << 16);
                pw[2 * kf1 + 1] = bf16bits(p2) | ((unsigned)bf16bits(p3) << 16);
            }
            uint4 pk = {pw[0], pw[1], pw[2], pw[3]};
            const bf16x8 pa = __builtin_bit_cast(bf16x8, pk);

            __builtin_amdgcn_s_setprio(1);
            #pragma unroll
            for (int n = 0; n < 4; ++n) {
                bf16x8 av = ldsx8(vsb + voff[c][n]);
                accO[n] = __builtin_amdgcn_mfma_f32_16x16x32_bf16(av, pa, accO[n], 0, 0, 0);
            }
            accL = __builtin_amdgcn_mfma_f32_16x16x32_bf16(onesf, pa, accL, 0, 0, 0);
            __builtin_amdgcn_s_setprio(0);
        }
        __syncthreads();
        cur ^= 1;
    }

    // L[q=lr] lives in accL[0] of lanes 0..15 (lg==0, r==0)
    const float inv = 1.0f / __shfl(accL[0], lr);

    bf16_t* obase = ctx + ((size_t)(b * S_ + q0w + lr) << 10) + h * 64;
    #pragma unroll
    for (int n = 0; n < 4; ++n) {
        ushort4 o;
        o.x = bf16bits(accO[n][0] * inv);
        o.y = bf16bits(accO[n][1] * inv);
        o.z = bf16bits(accO[n][2] * inv);
        o.w = bf16bits(accO[n][3] * inv);
        *(ushort4*)(obase + n * 16 + lg * 4) = o;
    }
}

// ---------------------------------------------------------------------------
// Fused prep: x cast + all 5 weight transpose/converts, one launch.
// ---------------------------------------------------------------------------
__global__ __launch_bounds__(256) void prep_all(
    const float* __restrict__ x, bf16_t* __restrict__ xb,
    const float* __restrict__ Wq, const float* __restrict__ Wk,
    const float* __restrict__ Wv, bf16_t* __restrict__ WqkvT,
    const float* __restrict__ Wo, bf16_t* __restrict__ WoT,
    const float* __restrict__ W1, bf16_t* __restrict__ W1T,
    const float* __restrict__ W2, bf16_t* __restrict__ W2T)
{
    __shared__ float t[32][33];
    const int tid = threadIdx.x;
    int bid = blockIdx.x;

    if (bid < 4096) {               // x f32 -> bf16, 8 per thread
        int i = bid * 256 + tid;
        float4 a = ((const float4*)x)[i * 2];
        float4 b = ((const float4*)x)[i * 2 + 1];
        unsigned int p0 = bf16bits(a.x) | ((unsigned)bf16bits(a.y) << 16);
        unsigned int p1 = bf16bits(a.z) | ((unsigned)bf16bits(a.w) << 16);
        unsigned int p2 = bf16bits(b.x) | ((unsigned)bf16bits(b.y) << 16);
        unsigned int p3 = bf16bits(b.z) | ((unsigned)bf16bits(b.w) << 16);
        uint4 o = {p0, p1, p2, p3};
        ((uint4*)xb)[i] = o;
        return;
    }
    bid -= 4096;

    const float* in; bf16_t* out;
    int R, C, c0, r0;
    float scale = 1.0f;
    if (bid < 3072) {               // Wq/Wk/Wv [16][1024][64] -> per-head [64][1024]
        const int p = bid >> 10, r = bid & 1023;
        const int z = r >> 6, rem = r & 63;
        in  = (p == 0 ? Wq : p == 1 ? Wk : Wv) + z * 65536;
        out = WqkvT + p * 1048576 + z * 65536;
        R = 1024; C = 64;
        c0 = (rem & 1) * 32; r0 = (rem >> 1) * 32;
        if (p == 0) scale = QSCALE;
    } else if (bid < 4096) {        // Wo [1024][1024]
        const int r = bid - 3072;
        in = Wo; out = WoT; R = 1024; C = 1024;
        c0 = (r & 31) * 32; r0 = (r >> 5) * 32;
    } else if (bid < 4160) {        // W1 [1024][64]
        const int r = bid - 4096;
        in = W1; out = W1T; R = 1024; C = 64;
        c0 = (r & 1) * 32; r0 = (r >> 1) * 32;
    } else {                        // W2 [64][1024]
        const int r = bid - 4160;
        in = W2; out = W2T; R = 64; C = 1024;
        c0 = (r & 31) * 32; r0 = (r >> 5) * 32;
    }

    {
        int rr = tid >> 3, c4 = (tid & 7) * 4;
        float4 v = *(const float4*)&in[(size_t)(r0 + rr) * C + c0 + c4];
        t[rr][c4 + 0] = v.x * scale;
        t[rr][c4 + 1] = v.y * scale;
        t[rr][c4 + 2] = v.z * scale;
        t[rr][c4 + 3] = v.w * scale;
    }
    __syncthreads();
    {
        int c = tid >> 3, r4 = (tid & 7) * 4;
        ushort4 o;
        o.x = bf16bits(t[r4 + 0][c]);
        o.y = bf16bits(t[r4 + 1][c]);
        o.z = bf16bits(t[r4 + 2][c]);
        o.w = bf16bits(t[r4 + 3][c]);
        *(ushort4*)(out + (size_t)(c0 + c) * R + r0 + r4) = o;
    }
}

// ---------------------------------------------------------------------------
// Row LayerNorm over 1024, f32 in, f32 or bf16 out.
// ---------------------------------------------------------------------------
template<typename OutT>
__global__ __launch_bounds__(256) void ln_kernel(
    const float* __restrict__ in, const float* __restrict__ g,
    const float* __restrict__ bta, OutT* __restrict__ out)
{
    const int row = blockIdx.x;
    const int tid = threadIdx.x;
    const float* x = in + (size_t)row * E_;

    float4 xv = ((const float4*)x)[tid];
    float s  = xv.x + xv.y + xv.z + xv.w;
    float sq = xv.x * xv.x + xv.y * xv.y + xv.z * xv.z + xv.w * xv.w;
    #pragma unroll
    for (int off = 32; off > 0; off >>= 1) {
        s  += __shfl_down(s, off);
        sq += __shfl_down(sq, off);
    }
    __shared__ float ss[4], ssq[4];
    if ((tid & 63) == 0) { ss[tid >> 6] = s; ssq[tid >> 6] = sq; }
    __syncthreads();
    s  = ss[0] + ss[1] + ss[2] + ss[3];
    sq = ssq[0] + ssq[1] + ssq[2] + ssq[3];

    const float mean = s * (1.0f / E_);
    const float var  = sq * (1.0f / E_) - mean * mean;
    const float rstd = rsqrtf(var + 1e-5f);

    float4 gv = ((const float4*)g)[tid];
    float4 bv = ((const float4*)bta)[tid];
    float o0 = (xv.x - mean) * rstd * gv.x + bv.x;
    float o1 = (xv.y - mean) * rstd * gv.y + bv.y;
    float o2 = (xv.z - mean) * rstd * gv.z + bv.z;
    float o3 = (xv.w - mean) * rstd * gv.w + bv.w;
    if constexpr (sizeof(OutT) == 4) {
        float4 o = {o0, o1, o2, o3};
        ((float4*)(out + (size_t)row * E_))[tid] = o;
    } else {
        ushort4 o;
        o.x = bf16bits(o0); o.y = bf16bits(o1);
        o.z = bf16bits(o2); o.w = bf16bits(o3);
        *(ushort4*)((bf16_t*)out + (size_t)row * E_ + tid * 4) = o;
    }
}

// ---------------------------------------------------------------------------
extern "C" void kernel_launch(void* const* d_in, const int* in_sizes, int n_in,
                              void* d_out, int out_size, void* d_ws, size_t ws_size,
                              hipStream_t stream)
{
    const float* x    = (const float*)d_in[0];
    const int*   mask = (const int*)d_in[1];
    const float* Wq   = (const float*)d_in[2];
    const float* bq   = (const float*)d_in[3];
    const float* Wk   = (const float*)d_in[4];
    const float* bk   = (const float*)d_in[5];
    const float* Wv   = (const float*)d_in[6];
    const float* bv   = (const float*)d_in[7];
    const float* Wo   = (const float*)d_in[8];
    const float* bo   = (const float*)d_in[9];
    const float* g1   = (const float*)d_in[10];
    const float* b1   = (const float*)d_in[11];
    const float* W1   = (const float*)d_in[12];
    const float* c1   = (const float*)d_in[13];
    const float* W2   = (const float*)d_in[14];
    const float* c2   = (const float*)d_in[15];
    const float* g2   = (const float*)d_in[16];
    const float* b2   = (const float*)d_in[17];

    char* W = (char*)d_ws;                       // peak 109.3 MB
    bf16_t* xb    = (bf16_t*)(W + 0);            // 16 MB
    bf16_t* WqkvT = (bf16_t*)(W + 16777216);     //  6 MB [3][1024 n][1024 k]
    bf16_t* WoT   = (bf16_t*)(W + 23068672);     //  2 MB
    bf16_t* W1T   = (bf16_t*)(W + 25165824);     //  128K
    bf16_t* W2T   = (bf16_t*)(W + 25296896);     //  128K
    bf16_t* qbuf  = (bf16_t*)(W + 25427968);     // 16 MB [b,s,h,d]
    bf16_t* kbuf  = (bf16_t*)(W + 42205184);     // 16 MB [b,s,h,d]
    bf16_t* vtb   = (bf16_t*)(W + 58982400);     // 16 MB [bh][d][s] (direct)
    bf16_t* ctx   = (bf16_t*)(W + 75759616);     // 16 MB
    float*  t1    = (float*)(W + 25427968);      // 32 MB over q+k (dead)
    bf16_t* hb    = (bf16_t*)(W + 58982400);     // over vtb (dead)
    bf16_t* f1b   = (bf16_t*)(W + 0);            // over xb (dead)
    float*  f2    = (float*)(W + 75759616);      // 32 MB over ctx + tail
    float*  out   = (float*)d_out;

    // fused prep (1/sqrt(S)*log2e folded into Wq)
    prep_all<<<8320, 256, 0, stream>>>(x, xb, Wq, Wk, Wv, WqkvT,
                                       Wo, WoT, W1, W1T, W2, W2T);

    // fused QKV projection [8192 x 3072 x 1024]; V written pre-transposed
    gemm_bf16<128, 128, 2><<<dim3(24, 64), 256, 0, stream>>>(
        xb, WqkvT, nullptr, qbuf, kbuf, vtb, bq, bk, bv, M_, 3072, 1024);

    attn_mfma<<<dim3(1024), 512, 0, stream>>>(qbuf, kbuf, vtb, mask, ctx);

    // output projection -> f32 t1
    gemm_bf16<128, 128, 0><<<dim3(8, 64), 256, 0, stream>>>(
        ctx, WoT, t1, nullptr, nullptr, nullptr, bo, nullptr, nullptr, M_, 1024, 1024);

    ln_kernel<bf16_t><<<8192, 256, 0, stream>>>(t1, g1, b1, hb);

    // FFN1 (N=64) + exact GELU -> bf16
    gemm_bf16<32, 64, 1><<<dim3(1, 256), 256, 0, stream>>>(
        hb, W1T, nullptr, f1b, nullptr, nullptr, c1, nullptr, nullptr, M_, 64, 1024);

    // FFN2 (K=64) -> f32
    gemm_bf16<128, 128, 0><<<dim3(8, 64), 256, 0, stream>>>(
        f1b, W2T, f2, nullptr, nullptr, nullptr, c2, nullptr, nullptr, M_, 1024, 64);

    ln_kernel<float><<<8192, 256, 0, stream>>>(f2, g2, b2, out);
}

// Round 7
// 243.629 us; speedup vs baseline: 1.0233x; 1.0233x over previous
//
#include <hip/hip_runtime.h>
#include <math.h>

#define B_ 4
#define S_ 2048
#define E_ 1024
#define H_ 16
#define D_ 64
#define M_ (B_*S_)
// 1/sqrt(2048) * log2(e): scale folded into Wq/bq so softmax uses exp2 directly
#define QSCALE (0.022097086912079608f * 1.4426950408889634f)

typedef __bf16 bf16_t;
typedef __bf16 bf16x8 __attribute__((ext_vector_type(8)));
typedef float  f32x4  __attribute__((ext_vector_type(4)));

// async global->LDS, 16B per lane. LDS dest must be linear (base + lane*16).
__device__ __forceinline__ void gload_lds16(const void* g, void* l) {
    __builtin_amdgcn_global_load_lds(
        (const __attribute__((address_space(1))) void*)g,
        (__attribute__((address_space(3))) void*)l, 16, 0, 0);
}
__device__ __forceinline__ bf16x8 ldsx8(const void* p) {
    return __builtin_bit_cast(bf16x8, *(const uint4*)p);
}
__device__ __forceinline__ unsigned short bf16bits(float x) {
    return __builtin_bit_cast(unsigned short, (bf16_t)x);
}
// swizzle for K-tile QK^T A-frag read rows {32c + 8a + 4kf + b}: f = (b + 2a) & 7
__device__ __forceinline__ int fk(int row) { return ((row & 3) + 2 * ((row >> 3) & 3)) & 7; }

// ---------------------------------------------------------------------------
// bf16 MFMA GEMM, C = A[M,K] x Bt[N,K]^T. BK=64, 4 waves, wave tile (BM/2)x(BN/2).
// Grid flattened + bijective XCD swizzle (requires nwg % 8 == 0).
// MODE 0: bf16 out + bias. MODE 1: bf16 out + bias + exact GELU.
// MODE 2: QKV scatter; Q bias scaled by QSCALE; V written transposed as
//         vt[bh][d][s].
// ---------------------------------------------------------------------------
template<int BM, int BN, int MODE>
__global__ __launch_bounds__(256) void gemm_bf16(
    const bf16_t* __restrict__ A, const bf16_t* __restrict__ Bt,
    bf16_t* __restrict__ ob0, bf16_t* __restrict__ ob1, bf16_t* __restrict__ ob2,
    const float* __restrict__ bias0, const float* __restrict__ bias1,
    const float* __restrict__ bias2,
    int M, int N, int K)
{
    constexpr int FM = BM / 32, FN = BN / 32;
    __shared__ bf16_t As[BM * 64];
    __shared__ bf16_t Bs[BN * 64];

    const int tid = threadIdx.x;
    const int w   = tid >> 6;
    const int wr  = w >> 1, wc = w & 1;
    const int lr  = tid & 15;
    const int lg  = (tid >> 4) & 3;

    // XCD-bijective block swizzle: 8 contiguous chunks, one per XCD
    const int nwg  = gridDim.x * gridDim.y;
    int bidf = blockIdx.y * gridDim.x + blockIdx.x;
    bidf = (bidf & 7) * (nwg >> 3) + (bidf >> 3);
    const int bm = (bidf / gridDim.x) * BM;
    const int bn = (bidf % gridDim.x) * BN;

    f32x4 acc[FM][FN] = {};

    for (int kk = 0; kk < K; kk += 64) {
        __syncthreads();
        #pragma unroll
        for (int i = 0; i < BM / 32; ++i) {
            int idx = i * 256 + tid;
            int row = idx >> 3, slot = idx & 7;
            gload_lds16(A + (size_t)(bm + row) * K + kk + (slot ^ (row & 7)) * 8,
                        (char*)As + idx * 16);
        }
        #pragma unroll
        for (int i = 0; i < BN / 32; ++i) {
            int idx = i * 256 + tid;
            int row = idx >> 3, slot = idx & 7;
            gload_lds16(Bt + (size_t)(bn + row) * K + kk + (slot ^ (row & 7)) * 8,
                        (char*)Bs + idx * 16);
        }
        __syncthreads();

        #pragma unroll
        for (int h = 0; h < 2; ++h) {
            bf16x8 af[FM], bfr[FN];
            #pragma unroll
            for (int m = 0; m < FM; ++m) {
                int row = wr * (BM / 2) + m * 16 + lr;
                af[m] = ldsx8((char*)As + row * 128 + (((4 * h + lg) ^ (row & 7)) << 4));
            }
            #pragma unroll
            for (int n = 0; n < FN; ++n) {
                int col = wc * (BN / 2) + n * 16 + lr;
                bfr[n] = ldsx8((char*)Bs + col * 128 + (((4 * h + lg) ^ (col & 7)) << 4));
            }
            #pragma unroll
            for (int m = 0; m < FM; ++m)
                #pragma unroll
                for (int n = 0; n < FN; ++n)
                    acc[m][n] = __builtin_amdgcn_mfma_f32_16x16x32_bf16(
                        af[m], bfr[n], acc[m][n], 0, 0, 0);
        }
    }

    #pragma unroll
    for (int n = 0; n < FN; ++n) {
        const int gcol = bn + wc * (BN / 2) + n * 16 + lr;
        if constexpr (MODE == 2) {
            const int p = gcol >> 10, nn = gcol & 1023;
            const float bv = (p == 0) ? bias0[nn] * QSCALE
                           : (p == 1) ? bias1[nn] : bias2[nn];
            #pragma unroll
            for (int m = 0; m < FM; ++m) {
                const int grow0 = bm + wr * (BM / 2) + m * 16 + lg * 4;
                if (p == 2) {   // V: write transposed [bh][d][s], 4 s contiguous
                    ushort4 o;
                    o.x = bf16bits(acc[m][n][0] + bv);
                    o.y = bf16bits(acc[m][n][1] + bv);
                    o.z = bf16bits(acc[m][n][2] + bv);
                    o.w = bf16bits(acc[m][n][3] + bv);
                    const int bb = grow0 >> 11, s = grow0 & 2047;
                    *(ushort4*)(ob2 + (((size_t)(bb << 10) + nn) << 11) + s) = o;
                } else {
                    bf16_t* o = (p == 0) ? ob0 : ob1;
                    #pragma unroll
                    for (int r = 0; r < 4; ++r)
                        o[((size_t)(grow0 + r) << 10) + nn] = (bf16_t)(acc[m][n][r] + bv);
                }
            }
        } else {
            const float bv = bias0[gcol];
            #pragma unroll
            for (int m = 0; m < FM; ++m)
                #pragma unroll
                for (int r = 0; r < 4; ++r) {
                    const int grow = bm + wr * (BM / 2) + m * 16 + lg * 4 + r;
                    float v = acc[m][n][r] + bv;
                    if constexpr (MODE == 1)
                        v = 0.5f * v * (1.0f + erff(v * 0.70710678118654752f));
                    ob0[(size_t)grow * N + gcol] = (bf16_t)v;
                }
        }
    }
}

// ---------------------------------------------------------------------------
// MFMA flash attention, zero-shuffle P path.
// 4 waves x 32 q-rows = QBLK 128, KVBLK=64, double-buffered stage-early.
// grid 1024 blocks x 256 thr = 4 blocks/CU (LDS 40KB), 16 waves/CU, no VGPR pin.
// Swapped QK^T: S^T = mfma(K_frag, Q_frag); A-row->key permutation puts each
// lane's 8 exp'd P values exactly into the K=32 PV B-fragment.
// L accumulated by ones-row MFMA; exp2-domain scores (log2e folded into Wq).
// Mask via fminf{+3e38,-1e9}; exp2(-1e9)=0. 8 bh per XCD for K/V L2 locality.
// ---------------------------------------------------------------------------
__global__ __launch_bounds__(256) void attn_mfma(
    const bf16_t* __restrict__ qg, const bf16_t* __restrict__ kg,
    const bf16_t* __restrict__ vg, const int* __restrict__ mask,
    bf16_t* __restrict__ ctx)
{
    __shared__ bf16_t ks[2][64 * 64];   // [key][d] 128B rows, fk-swizzled
    __shared__ bf16_t vts[2][64 * 64];  // [d][key] 128B rows, row&7-swizzled
    __shared__ float  mrow[S_];

    const int tid = threadIdx.x;
    const int w   = tid >> 6;
    const int lr  = tid & 15;
    const int lg  = (tid >> 4) & 3;

    const int bid = blockIdx.x;
    const int xcd = bid & 7, kidx = bid >> 3;        // kidx in [0,128)
    const int bh  = xcd * 8 + (kidx >> 4);           // 8 bh per XCD
    const int xq  = kidx & 15;                       // 16 q-blocks of 128
    const int b   = bh >> 4, h = bh & 15;
    const int q0w = xq * 128 + w * 32;               // wave owns 32 q-rows

    for (int i = tid; i < S_; i += 256)
        mrow[i] = mask[b * S_ + i] ? 3.0e38f : -1.0e9f;

    // Q as B-fragments: lane holds Q[q0w + f*16 + lr][half*32 + lg*8 + j]
    bf16x8 aq[2][2];
    #pragma unroll
    for (int f = 0; f < 2; ++f) {
        const bf16_t* qp = qg + ((size_t)(b * S_ + q0w + f * 16 + lr) << 10) + h * 64 + lg * 8;
        aq[f][0] = ldsx8(qp);
        aq[f][1] = ldsx8(qp + 32);
    }

    // ones A-fragment (row 0 = 1.0) for L-via-MFMA
    bf16x8 onesf;
    {
        bf16_t o1 = (bf16_t)((lr == 0) ? 1.0f : 0.0f);
        #pragma unroll
        for (int j = 0; j < 8; ++j) onesf[j] = o1;
    }

    // precomputed LDS read byte-offsets
    int koff[2][2][2], voff[2][4];
    #pragma unroll
    for (int c = 0; c < 2; ++c) {
        #pragma unroll
        for (int kf1 = 0; kf1 < 2; ++kf1) {
            const int row = c * 32 + 8 * (lr >> 2) + 4 * kf1 + (lr & 3);
            const int f = fk(row);
            koff[c][kf1][0] = row * 128 + ((lg ^ f) << 4);
            koff[c][kf1][1] = row * 128 + (((4 + lg) ^ f) << 4);
        }
        #pragma unroll
        for (int n = 0; n < 4; ++n) {
            const int rowv = n * 16 + lr;
            voff[c][n] = rowv * 128 + (((4 * c + lg) ^ (rowv & 7)) << 4);
        }
    }

    // staging pointers (incremental): 2 issues each for K and V per tile
    const bf16_t* kptr[2];
    const bf16_t* vptr[2];
    char* kdst[2];
    char* vdst[2];
    #pragma unroll
    for (int it = 0; it < 2; ++it) {
        const int idx = it * 256 + tid;
        const int row = idx >> 3, slot = idx & 7;
        kptr[it] = kg + ((size_t)(b * S_ + row) << 10) + h * 64 + (slot ^ fk(row)) * 8;
        vptr[it] = vg + (((size_t)bh * 64 + row) << 11) + (slot ^ (row & 7)) * 8;
        kdst[it] = (char*)ks + idx * 16;
        vdst[it] = (char*)vts + idx * 16;
    }

    f32x4 accO[2][4] = {};
    f32x4 accL[2] = {};

    #pragma unroll
    for (int it = 0; it < 2; ++it) {
        gload_lds16(kptr[it], kdst[it]);
        gload_lds16(vptr[it], vdst[it]);
        kptr[it] += (size_t)64 << 10;
        vptr[it] += 64;
    }
    __syncthreads();

    int cur = 0;
    for (int t0 = 0; t0 < S_; t0 += 64) {
        if (t0 + 64 < S_) {
            const int nb = (cur ^ 1) << 13;
            #pragma unroll
            for (int it = 0; it < 2; ++it) {
                gload_lds16(kptr[it], kdst[it] + nb);
                gload_lds16(vptr[it], vdst[it] + nb);
                kptr[it] += (size_t)64 << 10;
                vptr[it] += 64;
            }
        }
        const char* ksb = (const char*)ks + (cur << 13);
        const char* vsb = (const char*)vts + (cur << 13);

        #pragma unroll
        for (int c = 0; c < 2; ++c) {
            unsigned int pw0[4], pw1[4];
            #pragma unroll
            for (int kf1 = 0; kf1 < 2; ++kf1) {
                bf16x8 a0 = ldsx8(ksb + koff[c][kf1][0]);
                bf16x8 a1 = ldsx8(ksb + koff[c][kf1][1]);
                f32x4 z0 = {}, z1 = {};
                __builtin_amdgcn_s_setprio(1);
                z0 = __builtin_amdgcn_mfma_f32_16x16x32_bf16(a0, aq[0][0], z0, 0, 0, 0);
                z0 = __builtin_amdgcn_mfma_f32_16x16x32_bf16(a1, aq[0][1], z0, 0, 0, 0);
                z1 = __builtin_amdgcn_mfma_f32_16x16x32_bf16(a0, aq[1][0], z1, 0, 0, 0);
                z1 = __builtin_amdgcn_mfma_f32_16x16x32_bf16(a1, aq[1][1], z1, 0, 0, 0);
                __builtin_amdgcn_s_setprio(0);
                const f32x4 cap = *(const f32x4*)&mrow[t0 + c * 32 + 8 * lg + 4 * kf1];
                const float p00 = __builtin_amdgcn_exp2f(fminf(z0[0], cap[0]));
                const float p01 = __builtin_amdgcn_exp2f(fminf(z0[1], cap[1]));
                const float p02 = __builtin_amdgcn_exp2f(fminf(z0[2], cap[2]));
                const float p03 = __builtin_amdgcn_exp2f(fminf(z0[3], cap[3]));
                const float p10 = __builtin_amdgcn_exp2f(fminf(z1[0], cap[0]));
                const float p11 = __builtin_amdgcn_exp2f(fminf(z1[1], cap[1]));
                const float p12 = __builtin_amdgcn_exp2f(fminf(z1[2], cap[2]));
                const float p13 = __builtin_amdgcn_exp2f(fminf(z1[3], cap[3]));
                pw0[2 * kf1]     = bf16bits(p00) | ((unsigned)bf16bits(p01) << 16);
                pw0[2 * kf1 + 1] = bf16bits(p02) | ((unsigned)bf16bits(p03) << 16);
                pw1[2 * kf1]     = bf16bits(p10) | ((unsigned)bf16bits(p11) << 16);
                pw1[2 * kf1 + 1] = bf16bits(p12) | ((unsigned)bf16bits(p13) << 16);
            }
            uint4 pk0 = {pw0[0], pw0[1], pw0[2], pw0[3]};
            uint4 pk1 = {pw1[0], pw1[1], pw1[2], pw1[3]};
            const bf16x8 pa0 = __builtin_bit_cast(bf16x8, pk0);
            const bf16x8 pa1 = __builtin_bit_cast(bf16x8, pk1);

            __builtin_amdgcn_s_setprio(1);
            #pragma unroll
            for (int n = 0; n < 4; ++n) {
                bf16x8 av = ldsx8(vsb + voff[c][n]);
                accO[0][n] = __builtin_amdgcn_mfma_f32_16x16x32_bf16(av, pa0, accO[0][n], 0, 0, 0);
                accO[1][n] = __builtin_amdgcn_mfma_f32_16x16x32_bf16(av, pa1, accO[1][n], 0, 0, 0);
            }
            accL[0] = __builtin_amdgcn_mfma_f32_16x16x32_bf16(onesf, pa0, accL[0], 0, 0, 0);
            accL[1] = __builtin_amdgcn_mfma_f32_16x16x32_bf16(onesf, pa1, accL[1], 0, 0, 0);
            __builtin_amdgcn_s_setprio(0);
        }
        __syncthreads();
        cur ^= 1;
    }

    // L[q=lr] lives in accL[f][0] of lanes 0..15
    #pragma unroll
    for (int f = 0; f < 2; ++f) {
        const float inv = 1.0f / __shfl(accL[f][0], lr);
        bf16_t* obase = ctx + ((size_t)(b * S_ + q0w + f * 16 + lr) << 10) + h * 64;
        #pragma unroll
        for (int n = 0; n < 4; ++n) {
            ushort4 o;
            o.x = bf16bits(accO[f][n][0] * inv);
            o.y = bf16bits(accO[f][n][1] * inv);
            o.z = bf16bits(accO[f][n][2] * inv);
            o.w = bf16bits(accO[f][n][3] * inv);
            *(ushort4*)(obase + n * 16 + lg * 4) = o;
        }
    }
}

// ---------------------------------------------------------------------------
// Fused prep: x cast + all 5 weight transpose/converts, one launch.
// ---------------------------------------------------------------------------
__global__ __launch_bounds__(256) void prep_all(
    const float* __restrict__ x, bf16_t* __restrict__ xb,
    const float* __restrict__ Wq, const float* __restrict__ Wk,
    const float* __restrict__ Wv, bf16_t* __restrict__ WqkvT,
    const float* __restrict__ Wo, bf16_t* __restrict__ WoT,
    const float* __restrict__ W1, bf16_t* __restrict__ W1T,
    const float* __restrict__ W2, bf16_t* __restrict__ W2T)
{
    __shared__ float t[32][33];
    const int tid = threadIdx.x;
    int bid = blockIdx.x;

    if (bid < 4096) {               // x f32 -> bf16, 8 per thread
        int i = bid * 256 + tid;
        float4 a = ((const float4*)x)[i * 2];
        float4 b = ((const float4*)x)[i * 2 + 1];
        unsigned int p0 = bf16bits(a.x) | ((unsigned)bf16bits(a.y) << 16);
        unsigned int p1 = bf16bits(a.z) | ((unsigned)bf16bits(a.w) << 16);
        unsigned int p2 = bf16bits(b.x) | ((unsigned)bf16bits(b.y) << 16);
        unsigned int p3 = bf16bits(b.z) | ((unsigned)bf16bits(b.w) << 16);
        uint4 o = {p0, p1, p2, p3};
        ((uint4*)xb)[i] = o;
        return;
    }
    bid -= 4096;

    const float* in; bf16_t* out;
    int R, C, c0, r0;
    float scale = 1.0f;
    if (bid < 3072) {               // Wq/Wk/Wv [16][1024][64] -> per-head [64][1024]
        const int p = bid >> 10, r = bid & 1023;
        const int z = r >> 6, rem = r & 63;
        in  = (p == 0 ? Wq : p == 1 ? Wk : Wv) + z * 65536;
        out = WqkvT + p * 1048576 + z * 65536;
        R = 1024; C = 64;
        c0 = (rem & 1) * 32; r0 = (rem >> 1) * 32;
        if (p == 0) scale = QSCALE;
    } else if (bid < 4096) {        // Wo [1024][1024]
        const int r = bid - 3072;
        in = Wo; out = WoT; R = 1024; C = 1024;
        c0 = (r & 31) * 32; r0 = (r >> 5) * 32;
    } else if (bid < 4160) {        // W1 [1024][64]
        const int r = bid - 4096;
        in = W1; out = W1T; R = 1024; C = 64;
        c0 = (r & 1) * 32; r0 = (r >> 1) * 32;
    } else {                        // W2 [64][1024]
        const int r = bid - 4160;
        in = W2; out = W2T; R = 64; C = 1024;
        c0 = (r & 31) * 32; r0 = (r >> 5) * 32;
    }

    {
        int rr = tid >> 3, c4 = (tid & 7) * 4;
        float4 v = *(const float4*)&in[(size_t)(r0 + rr) * C + c0 + c4];
        t[rr][c4 + 0] = v.x * scale;
        t[rr][c4 + 1] = v.y * scale;
        t[rr][c4 + 2] = v.z * scale;
        t[rr][c4 + 3] = v.w * scale;
    }
    __syncthreads();
    {
        int c = tid >> 3, r4 = (tid & 7) * 4;
        ushort4 o;
        o.x = bf16bits(t[r4 + 0][c]);
        o.y = bf16bits(t[r4 + 1][c]);
        o.z = bf16bits(t[r4 + 2][c]);
        o.w = bf16bits(t[r4 + 3][c]);
        *(ushort4*)(out + (size_t)(c0 + c) * R + r0 + r4) = o;
    }
}

// ---------------------------------------------------------------------------
// Row LayerNorm over 1024. InT: float or bf16; OutT: float or bf16.
// ---------------------------------------------------------------------------
template<typename InT, typename OutT>
__global__ __launch_bounds__(256) void ln_kernel(
    const InT* __restrict__ in, const float* __restrict__ g,
    const float* __restrict__ bta, OutT* __restrict__ out)
{
    const int row = blockIdx.x;
    const int tid = threadIdx.x;

    float x0, x1, x2, x3;
    if constexpr (sizeof(InT) == 4) {
        float4 xv = ((const float4*)(in + (size_t)row * E_))[tid];
        x0 = xv.x; x1 = xv.y; x2 = xv.z; x3 = xv.w;
    } else {
        ushort4 xv = *(const ushort4*)((const bf16_t*)in + (size_t)row * E_ + tid * 4);
        x0 = (float)__builtin_bit_cast(bf16_t, xv.x);
        x1 = (float)__builtin_bit_cast(bf16_t, xv.y);
        x2 = (float)__builtin_bit_cast(bf16_t, xv.z);
        x3 = (float)__builtin_bit_cast(bf16_t, xv.w);
    }
    float s  = x0 + x1 + x2 + x3;
    float sq = x0 * x0 + x1 * x1 + x2 * x2 + x3 * x3;
    #pragma unroll
    for (int off = 32; off > 0; off >>= 1) {
        s  += __shfl_down(s, off);
        sq += __shfl_down(sq, off);
    }
    __shared__ float ss[4], ssq[4];
    if ((tid & 63) == 0) { ss[tid >> 6] = s; ssq[tid >> 6] = sq; }
    __syncthreads();
    s  = ss[0] + ss[1] + ss[2] + ss[3];
    sq = ssq[0] + ssq[1] + ssq[2] + ssq[3];

    const float mean = s * (1.0f / E_);
    const float var  = sq * (1.0f / E_) - mean * mean;
    const float rstd = rsqrtf(var + 1e-5f);

    float4 gv = ((const float4*)g)[tid];
    float4 bv = ((const float4*)bta)[tid];
    float o0 = (x0 - mean) * rstd * gv.x + bv.x;
    float o1 = (x1 - mean) * rstd * gv.y + bv.y;
    float o2 = (x2 - mean) * rstd * gv.z + bv.z;
    float o3 = (x3 - mean) * rstd * gv.w + bv.w;
    if constexpr (sizeof(OutT) == 4) {
        float4 o = {o0, o1, o2, o3};
        ((float4*)((float*)out + (size_t)row * E_))[tid] = o;
    } else {
        ushort4 o;
        o.x = bf16bits(o0); o.y = bf16bits(o1);
        o.z = bf16bits(o2); o.w = bf16bits(o3);
        *(ushort4*)((bf16_t*)out + (size_t)row * E_ + tid * 4) = o;
    }
}

// ---------------------------------------------------------------------------
extern "C" void kernel_launch(void* const* d_in, const int* in_sizes, int n_in,
                              void* d_out, int out_size, void* d_ws, size_t ws_size,
                              hipStream_t stream)
{
    const float* x    = (const float*)d_in[0];
    const int*   mask = (const int*)d_in[1];
    const float* Wq   = (const float*)d_in[2];
    const float* bq   = (const float*)d_in[3];
    const float* Wk   = (const float*)d_in[4];
    const float* bk   = (const float*)d_in[5];
    const float* Wv   = (const float*)d_in[6];
    const float* bv   = (const float*)d_in[7];
    const float* Wo   = (const float*)d_in[8];
    const float* bo   = (const float*)d_in[9];
    const float* g1   = (const float*)d_in[10];
    const float* b1   = (const float*)d_in[11];
    const float* W1   = (const float*)d_in[12];
    const float* c1   = (const float*)d_in[13];
    const float* W2   = (const float*)d_in[14];
    const float* c2   = (const float*)d_in[15];
    const float* g2   = (const float*)d_in[16];
    const float* b2   = (const float*)d_in[17];

    char* W = (char*)d_ws;                       // peak ~92 MB
    bf16_t* xb    = (bf16_t*)(W + 0);            // 16 MB
    bf16_t* WqkvT = (bf16_t*)(W + 16777216);     //  6 MB [3][1024 n][1024 k]
    bf16_t* WoT   = (bf16_t*)(W + 23068672);     //  2 MB
    bf16_t* W1T   = (bf16_t*)(W + 25165824);     //  128K
    bf16_t* W2T   = (bf16_t*)(W + 25296896);     //  128K
    bf16_t* qbuf  = (bf16_t*)(W + 25427968);     // 16 MB [b,s,h,d]
    bf16_t* kbuf  = (bf16_t*)(W + 42205184);     // 16 MB [b,s,h,d]
    bf16_t* vtb   = (bf16_t*)(W + 58982400);     // 16 MB [bh][d][s] (direct)
    bf16_t* ctx   = (bf16_t*)(W + 75759616);     // 16 MB
    bf16_t* t1b   = (bf16_t*)(W + 25427968);     // 16 MB over qbuf (dead)
    bf16_t* hb    = (bf16_t*)(W + 58982400);     // over vtb (dead)
    bf16_t* f1b   = (bf16_t*)(W + 0);            // over xb (dead)
    bf16_t* f2b   = (bf16_t*)(W + 75759616);     // over ctx (dead)
    float*  out   = (float*)d_out;

    // fused prep (1/sqrt(S)*log2e folded into Wq)
    prep_all<<<8320, 256, 0, stream>>>(x, xb, Wq, Wk, Wv, WqkvT,
                                       Wo, WoT, W1, W1T, W2, W2T);

    // fused QKV projection [8192 x 3072 x 1024]; V written pre-transposed
    gemm_bf16<128, 128, 2><<<dim3(24, 64), 256, 0, stream>>>(
        xb, WqkvT, qbuf, kbuf, vtb, bq, bk, bv, M_, 3072, 1024);

    attn_mfma<<<dim3(1024), 256, 0, stream>>>(qbuf, kbuf, vtb, mask, ctx);

    // output projection -> bf16 t1
    gemm_bf16<128, 128, 0><<<dim3(8, 64), 256, 0, stream>>>(
        ctx, WoT, t1b, nullptr, nullptr, bo, nullptr, nullptr, M_, 1024, 1024);

    ln_kernel<bf16_t, bf16_t><<<8192, 256, 0, stream>>>(t1b, g1, b1, hb);

    // FFN1 (N=64) + exact GELU -> bf16
    gemm_bf16<32, 64, 1><<<dim3(1, 256), 256, 0, stream>>>(
        hb, W1T, f1b, nullptr, nullptr, c1, nullptr, nullptr, M_, 64, 1024);

    // FFN2 (K=64) -> bf16
    gemm_bf16<128, 128, 0><<<dim3(8, 64), 256, 0, stream>>>(
        f1b, W2T, f2b, nullptr, nullptr, c2, nullptr, nullptr, M_, 1024, 64);

    ln_kernel<bf16_t, float><<<8192, 256, 0, stream>>>(f2b, g2, b2, out);
}

// Round 8
// 232.750 us; speedup vs baseline: 1.0712x; 1.0467x over previous
//
#include <hip/hip_runtime.h>
#include <math.h>

#define B_ 4
#define S_ 2048
#define E_ 1024
#define H_ 16
#define D_ 64
#define M_ (B_*S_)
// 1/sqrt(2048) * log2(e): scale folded into Wq/bq so softmax uses exp2 directly
#define QSCALE (0.022097086912079608f * 1.4426950408889634f)

typedef __bf16 bf16_t;
typedef __bf16 bf16x8 __attribute__((ext_vector_type(8)));
typedef float  f32x4  __attribute__((ext_vector_type(4)));

// async global->LDS, 16B per lane. LDS dest must be linear (base + lane*16).
__device__ __forceinline__ void gload_lds16(const void* g, void* l) {
    __builtin_amdgcn_global_load_lds(
        (const __attribute__((address_space(1))) void*)g,
        (__attribute__((address_space(3))) void*)l, 16, 0, 0);
}
__device__ __forceinline__ bf16x8 ldsx8(const void* p) {
    return __builtin_bit_cast(bf16x8, *(const uint4*)p);
}
__device__ __forceinline__ unsigned short bf16bits(float x) {
    return __builtin_bit_cast(unsigned short, (bf16_t)x);
}
// swizzle for K-tile QK^T A-frag read rows {32c + 8a + 4kf + b}: f = (b + 2a) & 7
__device__ __forceinline__ int fk(int row) { return ((row & 3) + 2 * ((row >> 3) & 3)) & 7; }

// ---------------------------------------------------------------------------
// bf16 MFMA GEMM, C = A[M,K] x Bt[N,K]^T. BK=64, 4 waves, wave tile (BM/2)x(BN/2).
// Grid flattened + bijective XCD swizzle (requires nwg % 8 == 0).
// MODE 0: bf16 out + bias. MODE 1: bf16 out + bias + exact GELU.
// MODE 2: QKV scatter; Q bias scaled by QSCALE; V written transposed as
//         vt[bh][d][s].
// ---------------------------------------------------------------------------
template<int BM, int BN, int MODE>
__global__ __launch_bounds__(256) void gemm_bf16(
    const bf16_t* __restrict__ A, const bf16_t* __restrict__ Bt,
    bf16_t* __restrict__ ob0, bf16_t* __restrict__ ob1, bf16_t* __restrict__ ob2,
    const float* __restrict__ bias0, const float* __restrict__ bias1,
    const float* __restrict__ bias2,
    int M, int N, int K)
{
    constexpr int FM = BM / 32, FN = BN / 32;
    __shared__ bf16_t As[BM * 64];
    __shared__ bf16_t Bs[BN * 64];

    const int tid = threadIdx.x;
    const int w   = tid >> 6;
    const int wr  = w >> 1, wc = w & 1;
    const int lr  = tid & 15;
    const int lg  = (tid >> 4) & 3;

    // XCD-bijective block swizzle: 8 contiguous chunks, one per XCD
    const int nwg  = gridDim.x * gridDim.y;
    int bidf = blockIdx.y * gridDim.x + blockIdx.x;
    bidf = (bidf & 7) * (nwg >> 3) + (bidf >> 3);
    const int bm = (bidf / gridDim.x) * BM;
    const int bn = (bidf % gridDim.x) * BN;

    f32x4 acc[FM][FN] = {};

    for (int kk = 0; kk < K; kk += 64) {
        __syncthreads();
        #pragma unroll
        for (int i = 0; i < BM / 32; ++i) {
            int idx = i * 256 + tid;
            int row = idx >> 3, slot = idx & 7;
            gload_lds16(A + (size_t)(bm + row) * K + kk + (slot ^ (row & 7)) * 8,
                        (char*)As + idx * 16);
        }
        #pragma unroll
        for (int i = 0; i < BN / 32; ++i) {
            int idx = i * 256 + tid;
            int row = idx >> 3, slot = idx & 7;
            gload_lds16(Bt + (size_t)(bn + row) * K + kk + (slot ^ (row & 7)) * 8,
                        (char*)Bs + idx * 16);
        }
        __syncthreads();

        #pragma unroll
        for (int h = 0; h < 2; ++h) {
            bf16x8 af[FM], bfr[FN];
            #pragma unroll
            for (int m = 0; m < FM; ++m) {
                int row = wr * (BM / 2) + m * 16 + lr;
                af[m] = ldsx8((char*)As + row * 128 + (((4 * h + lg) ^ (row & 7)) << 4));
            }
            #pragma unroll
            for (int n = 0; n < FN; ++n) {
                int col = wc * (BN / 2) + n * 16 + lr;
                bfr[n] = ldsx8((char*)Bs + col * 128 + (((4 * h + lg) ^ (col & 7)) << 4));
            }
            #pragma unroll
            for (int m = 0; m < FM; ++m)
                #pragma unroll
                for (int n = 0; n < FN; ++n)
                    acc[m][n] = __builtin_amdgcn_mfma_f32_16x16x32_bf16(
                        af[m], bfr[n], acc[m][n], 0, 0, 0);
        }
    }

    #pragma unroll
    for (int n = 0; n < FN; ++n) {
        const int gcol = bn + wc * (BN / 2) + n * 16 + lr;
        if constexpr (MODE == 2) {
            const int p = gcol >> 10, nn = gcol & 1023;
            const float bv = (p == 0) ? bias0[nn] * QSCALE
                           : (p == 1) ? bias1[nn] : bias2[nn];
            #pragma unroll
            for (int m = 0; m < FM; ++m) {
                const int grow0 = bm + wr * (BM / 2) + m * 16 + lg * 4;
                if (p == 2) {   // V: write transposed [bh][d][s], 4 s contiguous
                    ushort4 o;
                    o.x = bf16bits(acc[m][n][0] + bv);
                    o.y = bf16bits(acc[m][n][1] + bv);
                    o.z = bf16bits(acc[m][n][2] + bv);
                    o.w = bf16bits(acc[m][n][3] + bv);
                    const int bb = grow0 >> 11, s = grow0 & 2047;
                    *(ushort4*)(ob2 + (((size_t)(bb << 10) + nn) << 11) + s) = o;
                } else {
                    bf16_t* o = (p == 0) ? ob0 : ob1;
                    #pragma unroll
                    for (int r = 0; r < 4; ++r)
                        o[((size_t)(grow0 + r) << 10) + nn] = (bf16_t)(acc[m][n][r] + bv);
                }
            }
        } else {
            const float bv = bias0[gcol];
            #pragma unroll
            for (int m = 0; m < FM; ++m)
                #pragma unroll
                for (int r = 0; r < 4; ++r) {
                    const int grow = bm + wr * (BM / 2) + m * 16 + lg * 4 + r;
                    float v = acc[m][n][r] + bv;
                    if constexpr (MODE == 1)
                        v = 0.5f * v * (1.0f + erff(v * 0.70710678118654752f));
                    ob0[(size_t)grow * N + gcol] = (bf16_t)v;
                }
        }
    }
}

// ---------------------------------------------------------------------------
// MFMA flash attention, zero-shuffle P path, mask-as-accumulator-init.
// 4 waves x 32 q-rows = QBLK 128, KVBLK=64, double-buffered stage-early,
// tile loop unrolled x2 (static buffer indices).
// Swapped QK^T: S^T = mfma(K_frag, Q_frag, bias) where bias[key] in {0,-1e9}
// rides in as C-in -> no per-element mask op; exp2(z) underflows to 0 for
// masked keys (== reference -1e9 semantics). A-row->key permutation puts each
// lane's 8 exp'd P values exactly into the K=32 PV B-fragment.
// L accumulated by ones-row MFMA; exp2-domain scores (log2e folded into Wq).
// 8 bh per XCD for K/V L2 locality.
// ---------------------------------------------------------------------------
__global__ __launch_bounds__(256) void attn_mfma(
    const bf16_t* __restrict__ qg, const bf16_t* __restrict__ kg,
    const bf16_t* __restrict__ vg, const int* __restrict__ mask,
    bf16_t* __restrict__ ctx)
{
    __shared__ bf16_t ks[2][64 * 64];   // [key][d] 128B rows, fk-swizzled
    __shared__ bf16_t vts[2][64 * 64];  // [d][key] 128B rows, row&7-swizzled
    __shared__ float  mrow[S_];         // f32 additive bias: 0 or -1e9

    const int tid = threadIdx.x;
    const int w   = tid >> 6;
    const int lr  = tid & 15;
    const int lg  = (tid >> 4) & 3;

    const int bid = blockIdx.x;
    const int xcd = bid & 7, kidx = bid >> 3;        // kidx in [0,128)
    const int bh  = xcd * 8 + (kidx >> 4);           // 8 bh per XCD
    const int xq  = kidx & 15;                       // 16 q-blocks of 128
    const int b   = bh >> 4, h = bh & 15;
    const int q0w = xq * 128 + w * 32;               // wave owns 32 q-rows

    for (int i = tid; i < S_; i += 256)
        mrow[i] = mask[b * S_ + i] ? 0.0f : -1.0e9f;

    // Q as B-fragments: lane holds Q[q0w + f*16 + lr][half*32 + lg*8 + j]
    bf16x8 aq[2][2];
    #pragma unroll
    for (int f = 0; f < 2; ++f) {
        const bf16_t* qp = qg + ((size_t)(b * S_ + q0w + f * 16 + lr) << 10) + h * 64 + lg * 8;
        aq[f][0] = ldsx8(qp);
        aq[f][1] = ldsx8(qp + 32);
    }

    // ones A-fragment (row 0 = 1.0) for L-via-MFMA
    bf16x8 onesf;
    {
        bf16_t o1 = (bf16_t)((lr == 0) ? 1.0f : 0.0f);
        #pragma unroll
        for (int j = 0; j < 8; ++j) onesf[j] = o1;
    }

    // precomputed LDS read byte-offsets
    int koff[2][2][2], voff[2][4];
    #pragma unroll
    for (int c = 0; c < 2; ++c) {
        #pragma unroll
        for (int kf1 = 0; kf1 < 2; ++kf1) {
            const int row = c * 32 + 8 * (lr >> 2) + 4 * kf1 + (lr & 3);
            const int f = fk(row);
            koff[c][kf1][0] = row * 128 + ((lg ^ f) << 4);
            koff[c][kf1][1] = row * 128 + (((4 + lg) ^ f) << 4);
        }
        #pragma unroll
        for (int n = 0; n < 4; ++n) {
            const int rowv = n * 16 + lr;
            voff[c][n] = rowv * 128 + (((4 * c + lg) ^ (rowv & 7)) << 4);
        }
    }

    // staging pointers (incremental): 2 issues each for K and V per tile
    const bf16_t* kptr[2];
    const bf16_t* vptr[2];
    char* kdst[2];
    char* vdst[2];
    #pragma unroll
    for (int it = 0; it < 2; ++it) {
        const int idx = it * 256 + tid;
        const int row = idx >> 3, slot = idx & 7;
        kptr[it] = kg + ((size_t)(b * S_ + row) << 10) + h * 64 + (slot ^ fk(row)) * 8;
        vptr[it] = vg + (((size_t)bh * 64 + row) << 11) + (slot ^ (row & 7)) * 8;
        kdst[it] = (char*)ks + idx * 16;
        vdst[it] = (char*)vts + idx * 16;
    }

    f32x4 accO[2][4] = {};
    f32x4 accL[2] = {};

    auto STAGE = [&](int buf) {
        const int nb = buf << 13;
        #pragma unroll
        for (int it = 0; it < 2; ++it) {
            gload_lds16(kptr[it], kdst[it] + nb);
            gload_lds16(vptr[it], vdst[it] + nb);
            kptr[it] += (size_t)64 << 10;
            vptr[it] += 64;
        }
    };

    auto COMPUTE = [&](int buf, int t0) {
        const char* ksb = (const char*)ks + (buf << 13);
        const char* vsb = (const char*)vts + (buf << 13);
        #pragma unroll
        for (int c = 0; c < 2; ++c) {
            unsigned int pw0[4], pw1[4];
            #pragma unroll
            for (int kf1 = 0; kf1 < 2; ++kf1) {
                bf16x8 a0 = ldsx8(ksb + koff[c][kf1][0]);
                bf16x8 a1 = ldsx8(ksb + koff[c][kf1][1]);
                const f32x4 bias = *(const f32x4*)&mrow[t0 + c * 32 + 8 * lg + 4 * kf1];
                f32x4 z0 = bias, z1 = bias;
                __builtin_amdgcn_s_setprio(1);
                z0 = __builtin_amdgcn_mfma_f32_16x16x32_bf16(a0, aq[0][0], z0, 0, 0, 0);
                z0 = __builtin_amdgcn_mfma_f32_16x16x32_bf16(a1, aq[0][1], z0, 0, 0, 0);
                z1 = __builtin_amdgcn_mfma_f32_16x16x32_bf16(a0, aq[1][0], z1, 0, 0, 0);
                z1 = __builtin_amdgcn_mfma_f32_16x16x32_bf16(a1, aq[1][1], z1, 0, 0, 0);
                __builtin_amdgcn_s_setprio(0);
                const float p00 = __builtin_amdgcn_exp2f(z0[0]);
                const float p01 = __builtin_amdgcn_exp2f(z0[1]);
                const float p02 = __builtin_amdgcn_exp2f(z0[2]);
                const float p03 = __builtin_amdgcn_exp2f(z0[3]);
                const float p10 = __builtin_amdgcn_exp2f(z1[0]);
                const float p11 = __builtin_amdgcn_exp2f(z1[1]);
                const float p12 = __builtin_amdgcn_exp2f(z1[2]);
                const float p13 = __builtin_amdgcn_exp2f(z1[3]);
                pw0[2 * kf1]     = bf16bits(p00) | ((unsigned)bf16bits(p01) << 16);
                pw0[2 * kf1 + 1] = bf16bits(p02) | ((unsigned)bf16bits(p03) << 16);
                pw1[2 * kf1]     = bf16bits(p10) | ((unsigned)bf16bits(p11) << 16);
                pw1[2 * kf1 + 1] = bf16bits(p12) | ((unsigned)bf16bits(p13) << 16);
            }
            uint4 pk0 = {pw0[0], pw0[1], pw0[2], pw0[3]};
            uint4 pk1 = {pw1[0], pw1[1], pw1[2], pw1[3]};
            const bf16x8 pa0 = __builtin_bit_cast(bf16x8, pk0);
            const bf16x8 pa1 = __builtin_bit_cast(bf16x8, pk1);

            __builtin_amdgcn_s_setprio(1);
            #pragma unroll
            for (int n = 0; n < 4; ++n) {
                bf16x8 av = ldsx8(vsb + voff[c][n]);
                accO[0][n] = __builtin_amdgcn_mfma_f32_16x16x32_bf16(av, pa0, accO[0][n], 0, 0, 0);
                accO[1][n] = __builtin_amdgcn_mfma_f32_16x16x32_bf16(av, pa1, accO[1][n], 0, 0, 0);
            }
            accL[0] = __builtin_amdgcn_mfma_f32_16x16x32_bf16(onesf, pa0, accL[0], 0, 0, 0);
            accL[1] = __builtin_amdgcn_mfma_f32_16x16x32_bf16(onesf, pa1, accL[1], 0, 0, 0);
            __builtin_amdgcn_s_setprio(0);
        }
    };

    STAGE(0);
    __syncthreads();

    for (int t0 = 0; t0 < S_; t0 += 128) {
        STAGE(1);                       // stage t0+64 into buf1
        COMPUTE(0, t0);
        __syncthreads();
        if (t0 + 128 < S_) STAGE(0);    // stage t0+128 into buf0
        COMPUTE(1, t0 + 64);
        __syncthreads();
    }

    // L[q=lr] lives in accL[f][0] of lanes 0..15
    #pragma unroll
    for (int f = 0; f < 2; ++f) {
        const float inv = 1.0f / __shfl(accL[f][0], lr);
        bf16_t* obase = ctx + ((size_t)(b * S_ + q0w + f * 16 + lr) << 10) + h * 64;
        #pragma unroll
        for (int n = 0; n < 4; ++n) {
            ushort4 o;
            o.x = bf16bits(accO[f][n][0] * inv);
            o.y = bf16bits(accO[f][n][1] * inv);
            o.z = bf16bits(accO[f][n][2] * inv);
            o.w = bf16bits(accO[f][n][3] * inv);
            *(ushort4*)(obase + n * 16 + lg * 4) = o;
        }
    }
}

// ---------------------------------------------------------------------------
// Fused prep: x cast + all 5 weight transpose/converts, one launch.
// ---------------------------------------------------------------------------
__global__ __launch_bounds__(256) void prep_all(
    const float* __restrict__ x, bf16_t* __restrict__ xb,
    const float* __restrict__ Wq, const float* __restrict__ Wk,
    const float* __restrict__ Wv, bf16_t* __restrict__ WqkvT,
    const float* __restrict__ Wo, bf16_t* __restrict__ WoT,
    const float* __restrict__ W1, bf16_t* __restrict__ W1T,
    const float* __restrict__ W2, bf16_t* __restrict__ W2T)
{
    __shared__ float t[32][33];
    const int tid = threadIdx.x;
    int bid = blockIdx.x;

    if (bid < 4096) {               // x f32 -> bf16, 8 per thread
        int i = bid * 256 + tid;
        float4 a = ((const float4*)x)[i * 2];
        float4 b = ((const float4*)x)[i * 2 + 1];
        unsigned int p0 = bf16bits(a.x) | ((unsigned)bf16bits(a.y) << 16);
        unsigned int p1 = bf16bits(a.z) | ((unsigned)bf16bits(a.w) << 16);
        unsigned int p2 = bf16bits(b.x) | ((unsigned)bf16bits(b.y) << 16);
        unsigned int p3 = bf16bits(b.z) | ((unsigned)bf16bits(b.w) << 16);
        uint4 o = {p0, p1, p2, p3};
        ((uint4*)xb)[i] = o;
        return;
    }
    bid -= 4096;

    const float* in; bf16_t* out;
    int R, C, c0, r0;
    float scale = 1.0f;
    if (bid < 3072) {               // Wq/Wk/Wv [16][1024][64] -> per-head [64][1024]
        const int p = bid >> 10, r = bid & 1023;
        const int z = r >> 6, rem = r & 63;
        in  = (p == 0 ? Wq : p == 1 ? Wk : Wv) + z * 65536;
        out = WqkvT + p * 1048576 + z * 65536;
        R = 1024; C = 64;
        c0 = (rem & 1) * 32; r0 = (rem >> 1) * 32;
        if (p == 0) scale = QSCALE;
    } else if (bid < 4096) {        // Wo [1024][1024]
        const int r = bid - 3072;
        in = Wo; out = WoT; R = 1024; C = 1024;
        c0 = (r & 31) * 32; r0 = (r >> 5) * 32;
    } else if (bid < 4160) {        // W1 [1024][64]
        const int r = bid - 4096;
        in = W1; out = W1T; R = 1024; C = 64;
        c0 = (r & 1) * 32; r0 = (r >> 1) * 32;
    } else {                        // W2 [64][1024]
        const int r = bid - 4160;
        in = W2; out = W2T; R = 64; C = 1024;
        c0 = (r & 31) * 32; r0 = (r >> 5) * 32;
    }

    {
        int rr = tid >> 3, c4 = (tid & 7) * 4;
        float4 v = *(const float4*)&in[(size_t)(r0 + rr) * C + c0 + c4];
        t[rr][c4 + 0] = v.x * scale;
        t[rr][c4 + 1] = v.y * scale;
        t[rr][c4 + 2] = v.z * scale;
        t[rr][c4 + 3] = v.w * scale;
    }
    __syncthreads();
    {
        int c = tid >> 3, r4 = (tid & 7) * 4;
        ushort4 o;
        o.x = bf16bits(t[r4 + 0][c]);
        o.y = bf16bits(t[r4 + 1][c]);
        o.z = bf16bits(t[r4 + 2][c]);
        o.w = bf16bits(t[r4 + 3][c]);
        *(ushort4*)(out + (size_t)(c0 + c) * R + r0 + r4) = o;
    }
}

// ---------------------------------------------------------------------------
// Row LayerNorm over 1024. InT: float or bf16; OutT: float or bf16.
// ---------------------------------------------------------------------------
template<typename InT, typename OutT>
__global__ __launch_bounds__(256) void ln_kernel(
    const InT* __restrict__ in, const float* __restrict__ g,
    const float* __restrict__ bta, OutT* __restrict__ out)
{
    const int row = blockIdx.x;
    const int tid = threadIdx.x;

    float x0, x1, x2, x3;
    if constexpr (sizeof(InT) == 4) {
        float4 xv = ((const float4*)(in + (size_t)row * E_))[tid];
        x0 = xv.x; x1 = xv.y; x2 = xv.z; x3 = xv.w;
    } else {
        ushort4 xv = *(const ushort4*)((const bf16_t*)in + (size_t)row * E_ + tid * 4);
        x0 = (float)__builtin_bit_cast(bf16_t, xv.x);
        x1 = (float)__builtin_bit_cast(bf16_t, xv.y);
        x2 = (float)__builtin_bit_cast(bf16_t, xv.z);
        x3 = (float)__builtin_bit_cast(bf16_t, xv.w);
    }
    float s  = x0 + x1 + x2 + x3;
    float sq = x0 * x0 + x1 * x1 + x2 * x2 + x3 * x3;
    #pragma unroll
    for (int off = 32; off > 0; off >>= 1) {
        s  += __shfl_down(s, off);
        sq += __shfl_down(sq, off);
    }
    __shared__ float ss[4], ssq[4];
    if ((tid & 63) == 0) { ss[tid >> 6] = s; ssq[tid >> 6] = sq; }
    __syncthreads();
    s  = ss[0] + ss[1] + ss[2] + ss[3];
    sq = ssq[0] + ssq[1] + ssq[2] + ssq[3];

    const float mean = s * (1.0f / E_);
    const float var  = sq * (1.0f / E_) - mean * mean;
    const float rstd = rsqrtf(var + 1e-5f);

    float4 gv = ((const float4*)g)[tid];
    float4 bv = ((const float4*)bta)[tid];
    float o0 = (x0 - mean) * rstd * gv.x + bv.x;
    float o1 = (x1 - mean) * rstd * gv.y + bv.y;
    float o2 = (x2 - mean) * rstd * gv.z + bv.z;
    float o3 = (x3 - mean) * rstd * gv.w + bv.w;
    if constexpr (sizeof(OutT) == 4) {
        float4 o = {o0, o1, o2, o3};
        ((float4*)((float*)out + (size_t)row * E_))[tid] = o;
    } else {
        ushort4 o;
        o.x = bf16bits(o0); o.y = bf16bits(o1);
        o.z = bf16bits(o2); o.w = bf16bits(o3);
        *(ushort4*)((bf16_t*)out + (size_t)row * E_ + tid * 4) = o;
    }
}

// ---------------------------------------------------------------------------
extern "C" void kernel_launch(void* const* d_in, const int* in_sizes, int n_in,
                              void* d_out, int out_size, void* d_ws, size_t ws_size,
                              hipStream_t stream)
{
    const float* x    = (const float*)d_in[0];
    const int*   mask = (const int*)d_in[1];
    const float* Wq   = (const float*)d_in[2];
    const float* bq   = (const float*)d_in[3];
    const float* Wk   = (const float*)d_in[4];
    const float* bk   = (const float*)d_in[5];
    const float* Wv   = (const float*)d_in[6];
    const float* bv   = (const float*)d_in[7];
    const float* Wo   = (const float*)d_in[8];
    const float* bo   = (const float*)d_in[9];
    const float* g1   = (const float*)d_in[10];
    const float* b1   = (const float*)d_in[11];
    const float* W1   = (const float*)d_in[12];
    const float* c1   = (const float*)d_in[13];
    const float* W2   = (const float*)d_in[14];
    const float* c2   = (const float*)d_in[15];
    const float* g2   = (const float*)d_in[16];
    const float* b2   = (const float*)d_in[17];

    char* W = (char*)d_ws;                       // peak ~92 MB
    bf16_t* xb    = (bf16_t*)(W + 0);            // 16 MB
    bf16_t* WqkvT = (bf16_t*)(W + 16777216);     //  6 MB [3][1024 n][1024 k]
    bf16_t* WoT   = (bf16_t*)(W + 23068672);     //  2 MB
    bf16_t* W1T   = (bf16_t*)(W + 25165824);     //  128K
    bf16_t* W2T   = (bf16_t*)(W + 25296896);     //  128K
    bf16_t* qbuf  = (bf16_t*)(W + 25427968);     // 16 MB [b,s,h,d]
    bf16_t* kbuf  = (bf16_t*)(W + 42205184);     // 16 MB [b,s,h,d]
    bf16_t* vtb   = (bf16_t*)(W + 58982400);     // 16 MB [bh][d][s] (direct)
    bf16_t* ctx   = (bf16_t*)(W + 75759616);     // 16 MB
    bf16_t* t1b   = (bf16_t*)(W + 25427968);     // 16 MB over qbuf (dead)
    bf16_t* hb    = (bf16_t*)(W + 58982400);     // over vtb (dead)
    bf16_t* f1b   = (bf16_t*)(W + 0);            // over xb (dead)
    bf16_t* f2b   = (bf16_t*)(W + 75759616);     // over ctx (dead)
    float*  out   = (float*)d_out;

    // fused prep (1/sqrt(S)*log2e folded into Wq)
    prep_all<<<8320, 256, 0, stream>>>(x, xb, Wq, Wk, Wv, WqkvT,
                                       Wo, WoT, W1, W1T, W2, W2T);

    // fused QKV projection [8192 x 3072 x 1024]; V written pre-transposed
    gemm_bf16<128, 128, 2><<<dim3(24, 64), 256, 0, stream>>>(
        xb, WqkvT, qbuf, kbuf, vtb, bq, bk, bv, M_, 3072, 1024);

    attn_mfma<<<dim3(1024), 256, 0, stream>>>(qbuf, kbuf, vtb, mask, ctx);

    // output projection -> bf16 t1
    gemm_bf16<128, 128, 0><<<dim3(8, 64), 256, 0, stream>>>(
        ctx, WoT, t1b, nullptr, nullptr, bo, nullptr, nullptr, M_, 1024, 1024);

    ln_kernel<bf16_t, bf16_t><<<8192, 256, 0, stream>>>(t1b, g1, b1, hb);

    // FFN1 (N=64) + exact GELU -> bf16
    gemm_bf16<32, 64, 1><<<dim3(1, 256), 256, 0, stream>>>(
        hb, W1T, f1b, nullptr, nullptr, c1, nullptr, nullptr, M_, 64, 1024);

    // FFN2 (K=64) -> bf16
    gemm_bf16<128, 128, 0><<<dim3(8, 64), 256, 0, stream>>>(
        f1b, W2T, f2b, nullptr, nullptr, c2, nullptr, nullptr, M_, 1024, 64);

    ln_kernel<bf16_t, float><<<8192, 256, 0, stream>>>(f2b, g2, b2, out);
}